// Round 8
// baseline (90.650 us; speedup 1.0000x reference)
//
#include <hip/hip_runtime.h>
#include <hip/hip_bf16.h>

// Problem: B=128, M=256, T=512, N=512
// attn[b,0,n] = softmax_n( sum_k tanh(g[b,k] + sum_t X[b,t,n]*We2[t,k]) * v[k] )
// g[b,k] = (concat(hidden,cell)[b] @ We1)[k] + be1[k] + be2[k]   (bv cancels in softmax)
// k-sum is OUTSIDE tanh -> split k across blocks (ksl=2); partials summed in softmax.

typedef _Float16 half8 __attribute__((ext_vector_type(8)));
typedef float floatx4 __attribute__((ext_vector_type(4)));

// async global->LDS DMA, 16B per lane; LDS dest = wave-uniform base + lane*16
#define GLOAD_LDS16(gp, lp) __builtin_amdgcn_global_load_lds(                  \
    (const __attribute__((address_space(1))) void*)(const void*)(gp),          \
    (__attribute__((address_space(3))) void*)(void*)(lp), 16, 0, 0)

__device__ __forceinline__ float fast_tanh(float x) {
    float cx = fminf(15.0f, fmaxf(-15.0f, x));
    float e = __expf(2.0f * cx);
    return (e - 1.0f) * __fdividef(1.0f, e + 1.0f);
}

// ---------------- K0: Af slabs, per ts (32 t): chunk c = k-16-group 0..31,
// lane l: holds A[k=c*16+(l&15)][t=ts*32+(l>>4)*8+j], j=0..7 (A=We2^T, f16).
// Element offset: ts*16384 + c*512 + l*8.  Frag-linear => gload_lds-ready.
__global__ __launch_bounds__(256) void k_prep_a(const float* __restrict__ We2,
                                                _Float16* __restrict__ Af) {
    __shared__ float w2[32][512];
    const int ts = blockIdx.x;            // 16 blocks, t-range 32 each
    for (int idx = threadIdx.x; idx < 32 * 512; idx += 256) {
        int tl = idx >> 9, k = idx & 511;
        w2[tl][k] = We2[(ts * 32 + tl) * 512 + k];     // coalesced
    }
    __syncthreads();
    for (int item = threadIdx.x; item < 32 * 64; item += 256) {
        int c = item >> 6, l = item & 63;
        int k  = c * 16 + (l & 15);
        int tl = (l >> 4) * 8;
        half8 h;
#pragma unroll
        for (int j = 0; j < 8; ++j) h[j] = (_Float16)w2[tl + j][k];
        *(half8*)&Af[(((size_t)ts * 32 + c) * 64 + l) * 8] = h;   // coalesced
    }
}

// ---------------- K1: g[b][k] = hc@We1 + be1 + be2 ----------------
__global__ __launch_bounds__(256) void k_hs(const float* __restrict__ hidden,
                                            const float* __restrict__ cell,
                                            const float* __restrict__ We1,
                                            const float* __restrict__ be1,
                                            const float* __restrict__ be2,
                                            float* __restrict__ g) {
    __shared__ __align__(16) float hcl[8][512];
    __shared__ float red[4][8][64];
    const int b0 = (blockIdx.x >> 3) << 3;
    const int k0 = (blockIdx.x & 7) << 6;
    for (int idx = threadIdx.x; idx < 8 * 512; idx += 256) {
        int bi = idx >> 9, j = idx & 511;
        hcl[bi][j] = (j < 256) ? hidden[(b0 + bi) * 256 + j]
                               : cell[(b0 + bi) * 256 + j - 256];
    }
    __syncthreads();
    const int kl = threadIdx.x & 63;
    const int jc = threadIdx.x >> 6;
    const int k  = k0 + kl;
    float acc[8] = {};
    for (int j = jc * 128; j < jc * 128 + 128; j += 4) {
        float w0 = We1[(j + 0) * 512 + k];
        float w1 = We1[(j + 1) * 512 + k];
        float w2 = We1[(j + 2) * 512 + k];
        float w3 = We1[(j + 3) * 512 + k];
#pragma unroll
        for (int bi = 0; bi < 8; ++bi) {
            float4 h = *(const float4*)&hcl[bi][j];
            acc[bi] += h.x * w0 + h.y * w1 + h.z * w2 + h.w * w3;
        }
    }
#pragma unroll
    for (int bi = 0; bi < 8; ++bi) red[jc][bi][kl] = acc[bi];
    __syncthreads();
    for (int idx = threadIdx.x; idx < 512; idx += 256) {
        int bi = idx >> 6, kk = idx & 63;
        float s = red[0][bi][kk] + red[1][bi][kk] + red[2][bi][kk] + red[3][bi][kk];
        int kg = k0 + kk;
        g[(b0 + bi) * 512 + kg] = s + be1[kg] + be2[kg];
    }
}

// ---------------- K2: fused GEMM + tanh + v-dot -> E_part[b][n] ----------------
// grid = 128 b * 8 ntiles(64) * 2 kslices(256).  256 thr = 4 waves; wave wv
// owns k [ksl*256+wv*64, +64) (4 kf) x n 64 (4 nf) -> 16 MFMA / ts-step.
// Phase-structured: X[64n][256t] f16 staged per t-pass (cvt OUT of the main
// loop); A wave-PRIVATE LDS triple-buffer via global_load_lds, issued 2 steps
// ahead (vmcnt(8) waits only a ~2-step-old L2 DMA).  Main loop has ZERO
// barriers -> waves self-pace, memory jitter doesn't serialize the block.
// LDS 48(A)+32(X) = 80 KB -> exactly 2 blocks/CU.
__global__ __launch_bounds__(256, 2) void k_main(const float* __restrict__ X,
                                                 const _Float16* __restrict__ Af,
                                                 const float* __restrict__ g,
                                                 const float* __restrict__ vvec,
                                                 float* __restrict__ Ep) {
    __shared__ __align__(16) _Float16 Ab[24576];  // 48 KB: [wv][3buf][4kf][64l][8]
    __shared__ __align__(16) _Float16 Xb[16384];  // 32 KB: [8ts][4nf][64l][8]
    const int bid  = blockIdx.x;
    const int ksl  = bid & 1;
    const int nt   = (bid >> 1) & 7;
    const int b    = bid >> 4;
    const int n0   = nt << 6;
    const int tid  = threadIdx.x;
    const int lane = tid & 63;
    const int wv   = tid >> 6;        // 0..3
    const int l16  = lane & 15;
    const int lhi  = lane >> 4;       // 0..3

    const float* Xg = X + (size_t)b * (512 * 512) + n0;
    // A: wave-private k64 slice, chunks c0..c0+3, c0 = ksl*16 + wv*4
    const _Float16* AgW = Af + (size_t)(ksl * 16 + wv * 4) * 512 + (size_t)lane * 8;
    _Float16* AbW = &Ab[wv * 3 * 4 * 512 + lane * 8];   // + buf*2048 + kf*512

#define ISSUE_A(ts, buf)                                                       \
    {                                                                          \
        _Pragma("unroll")                                                      \
        for (int i = 0; i < 4; ++i)                                            \
            GLOAD_LDS16(AgW + (size_t)(ts) * 16384 + i * 512,                  \
                        AbW + (buf) * 2048 + i * 512);                         \
    }

    // X stage for pass p (t in [p*256, p*256+256)): 64 coalesced loads/thread
    const int xn = lane;              // n
    // slot for (it, n=xn, t-octet=wv): ((it*4 + (xn>>4))*64 + wv*16 + (xn&15))*8
    const int xsl = ((xn >> 4) * 64 + wv * 16 + (xn & 15)) * 8;
#define STAGE_X(p)                                                             \
    {                                                                          \
        _Pragma("unroll")                                                      \
        for (int it = 0; it < 8; ++it) {                                       \
            const int t0 = (p) * 256 + it * 32 + wv * 8;                       \
            float f[8];                                                        \
            _Pragma("unroll")                                                  \
            for (int j = 0; j < 8; ++j) f[j] = Xg[(size_t)(t0 + j) * 512 + xn];\
            half8 h;                                                           \
            _Pragma("unroll")                                                  \
            for (int j = 0; j < 8; ++j) h[j] = (_Float16)f[j];                 \
            *(half8*)&Xb[it * 2048 + xsl] = h;                                 \
        }                                                                      \
    }

#define LGKM_BARRIER()                                                         \
    {                                                                          \
        asm volatile("s_waitcnt lgkmcnt(0)" ::: "memory");                     \
        __builtin_amdgcn_sched_barrier(0);                                     \
        __builtin_amdgcn_s_barrier();                                          \
        __builtin_amdgcn_sched_barrier(0);                                     \
    }

    // ---- prologue: A(0),A(1) DMA in flight; stage X pass 0
    ISSUE_A(0, 0);
    ISSUE_A(1, 1);
    STAGE_X(0);
    LGKM_BARRIER();

    floatx4 acc[4][4];
#pragma unroll
    for (int a = 0; a < 4; ++a)
#pragma unroll
        for (int c = 0; c < 4; ++c) acc[a][c] = (floatx4){0.f, 0.f, 0.f, 0.f};

#define STEP(ts, lts)                                                          \
    {                                                                          \
        if ((ts) + 2 < 16) ISSUE_A((ts) + 2, ((ts) + 2) % 3);                  \
        if ((ts) < 14)                                                         \
            asm volatile("s_waitcnt vmcnt(8)" ::: "memory");                   \
        else if ((ts) == 14)                                                   \
            asm volatile("s_waitcnt vmcnt(4)" ::: "memory");                   \
        else                                                                   \
            asm volatile("s_waitcnt vmcnt(0)" ::: "memory");                   \
        __builtin_amdgcn_sched_barrier(0);                                     \
        const _Float16* ab = AbW + ((ts) % 3) * 2048;                          \
        half8 af0 = *(const half8*)(ab);                                       \
        half8 af1 = *(const half8*)(ab + 512);                                 \
        half8 af2 = *(const half8*)(ab + 1024);                                \
        half8 af3 = *(const half8*)(ab + 1536);                                \
        __builtin_amdgcn_s_setprio(1);                                         \
        _Pragma("unroll")                                                      \
        for (int nf = 0; nf < 4; ++nf) {                                       \
            half8 bf = *(const half8*)&Xb[((lts) * 4 + nf) * 512 + lane * 8];  \
            acc[0][nf] = __builtin_amdgcn_mfma_f32_16x16x32_f16(af0, bf, acc[0][nf], 0, 0, 0); \
            acc[1][nf] = __builtin_amdgcn_mfma_f32_16x16x32_f16(af1, bf, acc[1][nf], 0, 0, 0); \
            acc[2][nf] = __builtin_amdgcn_mfma_f32_16x16x32_f16(af2, bf, acc[2][nf], 0, 0, 0); \
            acc[3][nf] = __builtin_amdgcn_mfma_f32_16x16x32_f16(af3, bf, acc[3][nf], 0, 0, 0); \
        }                                                                      \
        __builtin_amdgcn_s_setprio(0);                                         \
    }

    // ---- pass 0: ts 0..7, barrier-free
#pragma unroll
    for (int lts = 0; lts < 8; ++lts) { STEP(lts, lts); }

    // ---- pass boundary: all Xb reads done -> restage -> visible
    LGKM_BARRIER();          // A(8),A(9) DMAs remain in flight (vmcnt untouched)
    STAGE_X(1);
    LGKM_BARRIER();

    // ---- pass 1: ts 8..15, barrier-free
#pragma unroll
    for (int lts = 0; lts < 8; ++lts) { STEP(8 + lts, lts); }

    // ---- fused epilogue: s[n] = sum_{k in slice} tanh(acc + g[k]) * v[k]
    // C/D layout (16x16x32): col n = lane&15, row k = (lane>>4)*4 + reg
    const float* gb = g + b * 512;
    float s[4] = {0.f, 0.f, 0.f, 0.f};
#pragma unroll
    for (int kf = 0; kf < 4; ++kf) {
        const int kb = ksl * 256 + wv * 64 + kf * 16 + lhi * 4;
        float g0 = gb[kb + 0], g1 = gb[kb + 1], g2 = gb[kb + 2], g3 = gb[kb + 3];
        float v0 = vvec[kb + 0], v1 = vvec[kb + 1], v2 = vvec[kb + 2], v3 = vvec[kb + 3];
#pragma unroll
        for (int nf = 0; nf < 4; ++nf) {
            s[nf] += fast_tanh(acc[kf][nf][0] + g0) * v0;
            s[nf] += fast_tanh(acc[kf][nf][1] + g1) * v1;
            s[nf] += fast_tanh(acc[kf][nf][2] + g2) * v2;
            s[nf] += fast_tanh(acc[kf][nf][3] + g3) * v3;
        }
    }
#pragma unroll
    for (int nf = 0; nf < 4; ++nf) {
        s[nf] += __shfl_xor(s[nf], 16);
        s[nf] += __shfl_xor(s[nf], 32);
    }
    __syncthreads();               // all waves done with LDS -> overlay on Xb
    float* ered = (float*)&Xb[0];  // [4 waves][64 n]
    if (lane < 16) {
#pragma unroll
        for (int nf = 0; nf < 4; ++nf) ered[wv * 64 + nf * 16 + l16] = s[nf];
    }
    __syncthreads();
    if (tid < 64) {
        float e = ered[tid] + ered[64 + tid] + ered[128 + tid] + ered[192 + tid];
        Ep[(size_t)ksl * (128 * 512) + b * 512 + n0 + tid] = e;
    }
#undef STEP
#undef STAGE_X
#undef ISSUE_A
#undef LGKM_BARRIER
}

// ---------------- K3: softmax over n (512) per batch row (sums partials) ----
__global__ __launch_bounds__(256) void k_softmax(const float* __restrict__ Ep,
                                                 float* __restrict__ out) {
    __shared__ float rmax[4], rsum[4];
    const int b = blockIdx.x;
    const int tid = threadIdx.x;
    const float* E0 = Ep;
    const float* E1 = Ep + 128 * 512;
    float e0 = E0[b * 512 + tid] + E1[b * 512 + tid];
    float e1 = E0[b * 512 + 256 + tid] + E1[b * 512 + 256 + tid];
    float m = fmaxf(e0, e1);
    for (int o = 32; o > 0; o >>= 1) m = fmaxf(m, __shfl_xor(m, o));
    if ((tid & 63) == 0) rmax[tid >> 6] = m;
    __syncthreads();
    m = fmaxf(fmaxf(rmax[0], rmax[1]), fmaxf(rmax[2], rmax[3]));
    float p0 = __expf(e0 - m), p1 = __expf(e1 - m);
    float ss = p0 + p1;
    for (int o = 32; o > 0; o >>= 1) ss += __shfl_xor(ss, o);
    if ((tid & 63) == 0) rsum[tid >> 6] = ss;
    __syncthreads();
    ss = rsum[0] + rsum[1] + rsum[2] + rsum[3];
    float inv = __fdividef(1.0f, ss);
    out[b * 512 + tid] = p0 * inv;
    out[b * 512 + 256 + tid] = p1 * inv;
}

extern "C" void kernel_launch(void* const* d_in, const int* in_sizes, int n_in,
                              void* d_out, int out_size, void* d_ws, size_t ws_size,
                              hipStream_t stream) {
    const float* hidden = (const float*)d_in[0];
    const float* cell   = (const float*)d_in[1];
    const float* X      = (const float*)d_in[2];
    const float* We1    = (const float*)d_in[3];
    const float* be1    = (const float*)d_in[4];
    const float* We2    = (const float*)d_in[5];
    const float* be2    = (const float*)d_in[6];
    const float* v      = (const float*)d_in[7];
    float* out = (float*)d_out;

    char* ws = (char*)d_ws;
    _Float16* Af = (_Float16*)ws;                        // 512*512*2       = 524288 B
    float* g     = (float*)(ws + 524288);                // 128*512*4       = 262144 B
    float* Ep    = (float*)(ws + 524288 + 262144);       // 2*128*512*4     = 524288 B

    k_prep_a<<<16, 256, 0, stream>>>(We2, Af);
    k_hs<<<128, 256, 0, stream>>>(hidden, cell, We1, be1, be2, g);
    k_main<<<2048, 256, 0, stream>>>(X, Af, g, v, Ep);
    k_softmax<<<128, 256, 0, stream>>>(Ep, out);
}

// Round 9
// 81.530 us; speedup vs baseline: 1.1119x; 1.1119x over previous
//
#include <hip/hip_runtime.h>
#include <hip/hip_bf16.h>

// Problem: B=128, M=256, T=512, N=512
// Reframed: C[m][k] = sum_t X[b][t][n]*We2[t][k],  m = b*512+n  (one 65536x512x512 GEMM)
// e[b][n] = sum_k tanh(C + g[b,k]) * v[k];  attn = softmax_n(e).
// k split over 4 blocks of 128 -> partials Ep[4], summed in softmax.

typedef _Float16 half8 __attribute__((ext_vector_type(8)));
typedef float floatx4 __attribute__((ext_vector_type(4)));

__device__ __forceinline__ float fast_tanh(float x) {
    float cx = fminf(15.0f, fmaxf(-15.0f, x));
    float e = __expf(2.0f * cx);
    return (e - 1.0f) * __fdividef(1.0f, e + 1.0f);
}

// ---------------- K0: Bf = We2 (f16) in frag-linear chunks ----------------
// chunk (kblk,ts) of 8192 elems; unit u=(h*8+c)*64+lane holds
// We2[t = ts*64 + h*32 + (lane>>4)*8 + j][k = kblk*128 + c*16 + (lane&15)].
__global__ __launch_bounds__(256) void k_prep_b(const float* __restrict__ We2,
                                                _Float16* __restrict__ Bf) {
    __shared__ float tl[64][133];
    const int kblk = blockIdx.x >> 3, ts = blockIdx.x & 7;
    const int k0 = kblk << 7, t0 = ts << 6;
    for (int idx = threadIdx.x; idx < 64 * 128; idx += 256) {
        int tr = idx >> 7, kc = idx & 127;
        tl[tr][kc] = We2[(t0 + tr) * 512 + k0 + kc];      // coalesced
    }
    __syncthreads();
    _Float16* dst = Bf + (size_t)(kblk * 8 + ts) * 8192;
#pragma unroll
    for (int i = 0; i < 4; ++i) {
        int s  = threadIdx.x + (i << 8);
        int h  = s >> 9, c = (s >> 6) & 7, ln = s & 63;
        int kl = c * 16 + (ln & 15);
        int tb = h * 32 + (ln >> 4) * 8;
        half8 hh;
#pragma unroll
        for (int j = 0; j < 8; ++j) hh[j] = (_Float16)tl[tb + j][kl];
        *(half8*)&dst[s * 8] = hh;                         // coalesced
    }
}

// ---------------- K1: g[b][k] = hc@We1 + be1 + be2 ----------------
__global__ __launch_bounds__(256) void k_hs(const float* __restrict__ hidden,
                                            const float* __restrict__ cell,
                                            const float* __restrict__ We1,
                                            const float* __restrict__ be1,
                                            const float* __restrict__ be2,
                                            float* __restrict__ g) {
    __shared__ __align__(16) float hcl[8][512];
    __shared__ float red[4][8][64];
    const int b0 = (blockIdx.x >> 3) << 3;
    const int k0 = (blockIdx.x & 7) << 6;
    for (int idx = threadIdx.x; idx < 8 * 512; idx += 256) {
        int bi = idx >> 9, j = idx & 511;
        hcl[bi][j] = (j < 256) ? hidden[(b0 + bi) * 256 + j]
                               : cell[(b0 + bi) * 256 + j - 256];
    }
    __syncthreads();
    const int kl = threadIdx.x & 63;
    const int jc = threadIdx.x >> 6;
    const int k  = k0 + kl;
    float acc[8] = {};
    for (int j = jc * 128; j < jc * 128 + 128; j += 4) {
        float w0 = We1[(j + 0) * 512 + k];
        float w1 = We1[(j + 1) * 512 + k];
        float w2 = We1[(j + 2) * 512 + k];
        float w3 = We1[(j + 3) * 512 + k];
#pragma unroll
        for (int bi = 0; bi < 8; ++bi) {
            float4 h = *(const float4*)&hcl[bi][j];
            acc[bi] += h.x * w0 + h.y * w1 + h.z * w2 + h.w * w3;
        }
    }
#pragma unroll
    for (int bi = 0; bi < 8; ++bi) red[jc][bi][kl] = acc[bi];
    __syncthreads();
    for (int idx = threadIdx.x; idx < 512; idx += 256) {
        int bi = idx >> 6, kk = idx & 63;
        float s = red[0][bi][kk] + red[1][bi][kk] + red[2][bi][kk] + red[3][bi][kk];
        int kg = k0 + kk;
        g[(b0 + bi) * 512 + kg] = s + be1[kg] + be2[kg];
    }
}

// ---------------- K2: GEMM tile 128m x 128k, BK=64, fused epilogue ----------
// grid 2048 = 512 mt x 4 kblk (XCD-swizzled so kblk-siblings share an XCD).
// 256 thr = 4 waves (2m x 2k); wave = 64m x 64k = acc 4x4; 32 MFMA / step.
// X: reg-staged f32->f16 into LDS dbuf 2x16KB (T14 issue-early/write-late).
// B: frag-direct global b128 reads from L2-hot Bf (no LDS, same-step use).
// LDS 32 KB + VGPR<=170 -> 3 blocks/CU of independent rhythm.
__global__ __launch_bounds__(256, 3) void k_main(const float* __restrict__ X,
                                                 const _Float16* __restrict__ Bf,
                                                 const float* __restrict__ g,
                                                 const float* __restrict__ vvec,
                                                 float* __restrict__ Ep) {
    __shared__ __align__(16) _Float16 Xs[2][8192];    // 2 x 16 KiB
    const int tid  = threadIdx.x;
    const int lane = tid & 63;
    const int wv   = tid >> 6;        // 0..3
    const int l16  = lane & 15;
    const int lhi  = lane >> 4;       // 0..3
    const int logical = ((blockIdx.x & 7) << 8) | (blockIdx.x >> 3);
    const int mt   = logical >> 2;
    const int kblk = logical & 3;
    const int b    = mt >> 2;
    const int n0   = (mt & 3) << 7;
    const int mw   = wv >> 1;         // m-half
    const int kw   = wv & 1;          // k-half

    const float* Xg = X + (size_t)b * 262144 + n0;
    // X staging slots: s = tid + i*256 -> (m = s&127, t-oct = (s>>7)&3, h = s>>9)
    int sm[4], st[4], su[4];
#pragma unroll
    for (int i = 0; i < 4; ++i) {
        int s  = tid + (i << 8);
        int m  = s & 127, lh = (s >> 7) & 3, h = s >> 9;
        sm[i] = m;
        st[i] = h * 32 + lh * 8;
        su[i] = ((h * 8 + (m >> 4)) * 64 + lh * 16 + (m & 15)) * 8;
    }
    // B frag base: frag (ts,h,nf) at Bw + ts*8192 + h*4096 + nf*512
    const _Float16* Bw = Bf + (size_t)kblk * 65536 + (size_t)kw * 2048 +
                         (size_t)lane * 8;

    float xr[32];
    // ---- prologue: stage X(0)
#pragma unroll
    for (int i = 0; i < 4; ++i)
#pragma unroll
        for (int j = 0; j < 8; ++j)
            xr[i * 8 + j] = Xg[(size_t)(st[i] + j) * 512 + sm[i]];
#pragma unroll
    for (int i = 0; i < 4; ++i) {
        half8 hh;
#pragma unroll
        for (int j = 0; j < 8; ++j) hh[j] = (_Float16)xr[i * 8 + j];
        *(half8*)&Xs[0][su[i]] = hh;
    }
    __syncthreads();

    floatx4 acc[4][4];
#pragma unroll
    for (int a = 0; a < 4; ++a)
#pragma unroll
        for (int c = 0; c < 4; ++c) acc[a][c] = (floatx4){0.f, 0.f, 0.f, 0.f};

#pragma unroll
    for (int ts = 0; ts < 8; ++ts) {
        const int cur = ts & 1, nxt = cur ^ 1;
        // 1. issue X(ts+1) loads early (consumed after compute -> HBM hidden)
        if (ts < 7) {
#pragma unroll
            for (int i = 0; i < 4; ++i)
#pragma unroll
                for (int j = 0; j < 8; ++j)
                    xr[i * 8 + j] =
                        Xg[(size_t)((ts + 1) * 64 + st[i] + j) * 512 + sm[i]];
        }
        __builtin_amdgcn_sched_barrier(0);   // pin issue point (anti-sink)
        // 2. compute: 2 halves x {4 A ds_read + 4 B global(L2) + 16 MFMA}
#pragma unroll
        for (int h = 0; h < 2; ++h) {
            half8 af[4], bf[4];
#pragma unroll
            for (int mf = 0; mf < 4; ++mf)
                af[mf] = *(const half8*)
                    &Xs[cur][((h * 8 + mw * 4 + mf) * 64 + lane) * 8];
#pragma unroll
            for (int nf = 0; nf < 4; ++nf)
                bf[nf] = *(const half8*)
                    (Bw + (size_t)ts * 8192 + h * 4096 + nf * 512);
#pragma unroll
            for (int mf = 0; mf < 4; ++mf)
#pragma unroll
                for (int nf = 0; nf < 4; ++nf)
                    acc[mf][nf] = __builtin_amdgcn_mfma_f32_16x16x32_f16(
                        af[mf], bf[nf], acc[mf][nf], 0, 0, 0);
        }
        // 3. cvt + write X(ts+1) late (T14)
        if (ts < 7) {
#pragma unroll
            for (int i = 0; i < 4; ++i) {
                half8 hh;
#pragma unroll
                for (int j = 0; j < 8; ++j) hh[j] = (_Float16)xr[i * 8 + j];
                *(half8*)&Xs[nxt][su[i]] = hh;
            }
        }
        __syncthreads();
    }

    // ---- fused epilogue ----
    // C layout: row m = mw*64 + mf*16 + lhi*4 + r ; col k_local = kw*64 + nf*16 + l16
    const float* gb = g + b * 512 + kblk * 128;
    const float* vb = vvec + kblk * 128;
    float sl[4][4];
#pragma unroll
    for (int mf = 0; mf < 4; ++mf)
#pragma unroll
        for (int r = 0; r < 4; ++r) sl[mf][r] = 0.f;
#pragma unroll
    for (int nf = 0; nf < 4; ++nf) {
        const int kl = kw * 64 + nf * 16 + l16;
        const float gv = gb[kl];
        const float vvl = vb[kl];
#pragma unroll
        for (int mf = 0; mf < 4; ++mf)
#pragma unroll
            for (int r = 0; r < 4; ++r)
                sl[mf][r] += fast_tanh(acc[mf][nf][r] + gv) * vvl;
    }
    // reduce over the 16 k-columns held across l16
#pragma unroll
    for (int mf = 0; mf < 4; ++mf)
#pragma unroll
        for (int r = 0; r < 4; ++r) {
            float x = sl[mf][r];
            x += __shfl_xor(x, 1);
            x += __shfl_xor(x, 2);
            x += __shfl_xor(x, 4);
            x += __shfl_xor(x, 8);
            sl[mf][r] = x;
        }
    __syncthreads();                       // all Xs reads done -> overlay
    float* ered = (float*)&Xs[0][0];       // [2 kw][128 m]
    if (l16 == 0) {
#pragma unroll
        for (int mf = 0; mf < 4; ++mf)
#pragma unroll
            for (int r = 0; r < 4; ++r)
                ered[kw * 128 + mw * 64 + mf * 16 + lhi * 4 + r] = sl[mf][r];
    }
    __syncthreads();
    if (tid < 128) {
        float e = ered[tid] + ered[128 + tid];
        Ep[(size_t)kblk * 65536 + b * 512 + n0 + tid] = e;
    }
}

// ---------------- K3: softmax over n (512), summing 4 k-partials ------------
__global__ __launch_bounds__(256) void k_softmax(const float* __restrict__ Ep,
                                                 float* __restrict__ out) {
    __shared__ float rmax[4], rsum[4];
    const int b = blockIdx.x;
    const int tid = threadIdx.x;
    float e0 = Ep[b * 512 + tid] + Ep[65536 + b * 512 + tid] +
               Ep[131072 + b * 512 + tid] + Ep[196608 + b * 512 + tid];
    float e1 = Ep[b * 512 + 256 + tid] + Ep[65536 + b * 512 + 256 + tid] +
               Ep[131072 + b * 512 + 256 + tid] + Ep[196608 + b * 512 + 256 + tid];
    float m = fmaxf(e0, e1);
    for (int o = 32; o > 0; o >>= 1) m = fmaxf(m, __shfl_xor(m, o));
    if ((tid & 63) == 0) rmax[tid >> 6] = m;
    __syncthreads();
    m = fmaxf(fmaxf(rmax[0], rmax[1]), fmaxf(rmax[2], rmax[3]));
    float p0 = __expf(e0 - m), p1 = __expf(e1 - m);
    float ss = p0 + p1;
    for (int o = 32; o > 0; o >>= 1) ss += __shfl_xor(ss, o);
    if ((tid & 63) == 0) rsum[tid >> 6] = ss;
    __syncthreads();
    ss = rsum[0] + rsum[1] + rsum[2] + rsum[3];
    float inv = __fdividef(1.0f, ss);
    out[b * 512 + tid] = p0 * inv;
    out[b * 512 + 256 + tid] = p1 * inv;
}

extern "C" void kernel_launch(void* const* d_in, const int* in_sizes, int n_in,
                              void* d_out, int out_size, void* d_ws, size_t ws_size,
                              hipStream_t stream) {
    const float* hidden = (const float*)d_in[0];
    const float* cell   = (const float*)d_in[1];
    const float* X      = (const float*)d_in[2];
    const float* We1    = (const float*)d_in[3];
    const float* be1    = (const float*)d_in[4];
    const float* We2    = (const float*)d_in[5];
    const float* be2    = (const float*)d_in[6];
    const float* v      = (const float*)d_in[7];
    float* out = (float*)d_out;

    char* ws = (char*)d_ws;
    _Float16* Bf = (_Float16*)ws;                        // 512*512*2   = 524288 B
    float* g     = (float*)(ws + 524288);                // 128*512*4   = 262144 B
    float* Ep    = (float*)(ws + 786432);                // 4*128*512*4 = 1048576 B

    k_prep_b<<<32, 256, 0, stream>>>(We2, Bf);
    k_hs<<<128, 256, 0, stream>>>(hidden, cell, We1, be1, be2, g);
    k_main<<<2048, 256, 0, stream>>>(X, Bf, g, v, Ep);
    k_softmax<<<128, 256, 0, stream>>>(Ep, out);
}